// Round 17
// baseline (236.748 us; speedup 1.0000x reference)
//
#include <hip/hip_runtime.h>
#include <hip/hip_bf16.h>

// Problem constants
#define NB 2
#define NN 2048
#define DIM 96
#define NH 4
#define DH 24
#define PD 16
#define SCALE 0.2041241452319315f   // 1/sqrt(24)
#define NEGBIG -1e30f
#define SCLAMP 30.0f                // exp-arg clamp; exact for realistic logits

typedef __attribute__((ext_vector_type(4))) short bf16x4;
typedef __attribute__((ext_vector_type(4))) float f32x4;
typedef __attribute__((ext_vector_type(4))) unsigned int u32x4;

static __device__ __forceinline__ short bfs(float x){
  __hip_bfloat16 h = __float2bfloat16(x);
  return __builtin_bit_cast(short, h);
}

static __device__ __forceinline__ float fastrcp(float x){
#if __has_builtin(__builtin_amdgcn_rcpf)
  return __builtin_amdgcn_rcpf(x);
#else
  return 1.f / x;
#endif
}

// bf16 halfword -> f32 (hi selects upper half of the u32)
static __device__ __forceinline__ float bfbits(unsigned int u, int hi){
  return __builtin_bit_cast(float, hi ? (u & 0xFFFF0000u) : (u << 16));
}

// D = A(16x16) * B(16x16) + C, bf16 in, f32 accum. Layout (lane l, x=l&15, g=l>>4):
//   A: A[row=x][k=g*4+i] ; B: B[k=g*4+i][col=x] ; C/D: D[row=g*4+r][col=x]
static __device__ __forceinline__ f32x4 mfma16(bf16x4 a, bf16x4 b, f32x4 c){
#if __has_builtin(__builtin_amdgcn_mfma_f32_16x16x16bf16_1k)
  return __builtin_amdgcn_mfma_f32_16x16x16bf16_1k(a, b, c, 0, 0, 0);
#else
  asm volatile("v_mfma_f32_16x16x16_bf16 %0, %1, %2, %0" : "+v"(c) : "v"(a), "v"(b));
  return c;
#endif
}

// ---------------- Kernel A: LayerNorm + QKV projection (8 rows/block) ----------------
// K/V written pre-swizzled into MFMA fragment order (R14 layout, verified):
//  K: kq2[(b*NH+h)*128 + jt] 1KB block: bytes l*8 = K[jt*16+(l&15)][k=(l>>4)*4..+3]
//     (k00), bytes 512+l*8 with k+=16 (k01; k>=24 zero).
//  V: vq2[((b*NH+h)*128 + jt)*2 + mf] 512B: bytes l*8 = V[jt*16+(l>>4)*4+i][mf*16+(l&15)].
__global__ __launch_bounds__(256) void kA(
    const float* __restrict__ nodes,
    const float* __restrict__ gamma, const float* __restrict__ beta,
    const float* __restrict__ Wq, const float* __restrict__ Wk, const float* __restrict__ Wv,
    __hip_bfloat16* __restrict__ qp, unsigned short* __restrict__ kq2,
    unsigned short* __restrict__ vq2)
{
  __shared__ __align__(16) float hl[8][100];
  const int b  = blockIdx.x >> 8;
  const int n0 = (blockIdx.x & 255) << 3;
  const int tid = threadIdx.x;
  const float* np = nodes + ((size_t)(b*NN + n0))*DIM;
  for (int idx = tid; idx < 8*DIM; idx += 256){
    const int r = idx/DIM; hl[r][idx - r*DIM] = np[idx];
  }
  __syncthreads();
  const int r8 = tid >> 5, c32 = tid & 31;
  float s = 0.f, s2 = 0.f;
  for (int k2 = c32; k2 < DIM; k2 += 32){ float v = hl[r8][k2]; s += v; s2 += v*v; }
  #pragma unroll
  for (int off = 1; off < 32; off <<= 1){ s += __shfl_xor(s, off); s2 += __shfl_xor(s2, off); }
  const float mu = s*(1.f/DIM);
  const float rs = rsqrtf(s2*(1.f/DIM) - mu*mu + 1e-5f);
  for (int k2 = c32; k2 < DIM; k2 += 32)
    hl[r8][k2] = (hl[r8][k2] - mu)*rs*gamma[k2] + beta[k2];
  __syncthreads();
  for (int c = tid; c < 3*DIM; c += 256){
    const int mat = c/DIM, d = c - mat*DIM;
    const float* W = (mat == 0) ? Wq : ((mat == 1) ? Wk : Wv);
    float acc[8];
    #pragma unroll
    for (int r = 0; r < 8; ++r) acc[r] = 0.f;
    #pragma unroll 4
    for (int kk = 0; kk < DIM; ++kk){
      const float w = W[kk*DIM + d];
      #pragma unroll
      for (int r = 0; r < 8; ++r) acc[r] += hl[r][kk] * w;
    }
    const int hh = d / DH, dh = d - hh*DH;
    if (mat == 0){
      #pragma unroll
      for (int r = 0; r < 8; ++r)
        qp[((size_t)(b*NN + n0 + r))*128 + hh*32 + dh] = __float2bfloat16(acc[r] * SCALE);
    } else if (mat == 1){
      const int halfsel = dh >> 4;
      const int gk = (dh - halfsel*16) >> 2;
      #pragma unroll
      for (int r = 0; r < 8; ++r){
        const int n = n0 + r;
        const size_t base = ((size_t)(b*NH + hh)*128 + (n>>4))*512;
        kq2[base + halfsel*256 + (gk*16 + (n&15))*4 + (dh&3)] =
            (unsigned short)bfs(acc[r]);
      }
    } else {
      const int mf = dh >> 4, xx = dh & 15;
      #pragma unroll
      for (int r = 0; r < 8; ++r){
        const int n = n0 + r;
        const size_t blk = ((size_t)(b*NH + hh)*128 + (n>>4))*2 + mf;
        vq2[blk*256 + (((n&15)>>2)*16 + xx)*4 + (n&3)] = (unsigned short)bfs(acc[r]);
      }
    }
  }
  {
    const int r = tid >> 5, hh = (tid >> 3) & 3, t = tid & 7;
    const int n = n0 + r;
    const int dh = 24 + t;
    qp[((size_t)(b*NN + n))*128 + hh*32 + dh] = __float2bfloat16(0.f);
    const size_t kbase = ((size_t)(b*NH + hh)*128 + (n>>4))*512;
    kq2[kbase + 256 + (((8 + t)>>2)*16 + (n&15))*4 + (dh&3)] = 0;
    const size_t vblk = ((size_t)(b*NH + hh)*128 + (n>>4))*2 + 1;
    vq2[vblk*256 + (((n&15)>>2)*16 + 8 + t)*4 + (n&3)] = 0;
  }
}

// ---------------- Kernel B: zipped pair-MLP + masked attention, distance-2 prefetch ----
// One wave = (b, 16-row i-tile, j-split); 64-wide j-tiles; S=8 -> 4 tiles/wave.
// R15 zip schedule with prefetch distance 2: four rotating reg buffers b0..b3
// (batch m's buffer = m&3, statically resolved since 8 batches/tile ≡ 0 mod 4).
__global__ __launch_bounds__(64, 2) void kB(
    const float* __restrict__ pair, const float* __restrict__ mask,
    const __hip_bfloat16* __restrict__ qp, const unsigned short* __restrict__ kq2,
    const unsigned short* __restrict__ vq2,
    const float* __restrict__ W1, const float* __restrict__ b1,
    const float* __restrict__ W2, const float* __restrict__ b2,
    float* __restrict__ Pctx, float* __restrict__ Pml, const int S)
{
  // rel bf16, double buffered per tile: [buf][il(16)][j(64)*4h + pad(8)] stride 264
  __shared__ __align__(16) unsigned short rl2[2*16*264];   // 16.9 KB
  const int lane = threadIdx.x & 63;
  const int gw   = blockIdx.x;
  const int s    = gw % S;
  const int it   = (gw / S) & 127;
  const int b    = gw / (S*128);
  const int i0   = it << 4;
  const int jchunk = NN / S;
  const int j0b  = s * jchunk;
  const int x = lane & 15, g = lane >> 4;

  bf16x4 w1t, w2t;
  f32x4 b1f, b2f;
  #pragma unroll
  for (int i = 0; i < 4; ++i){
    w1t[i] = bfs(W1[(g*4 + i)*16 + x]);
    w2t[i] = (x < 4) ? bfs(W2[(g*4 + i)*4 + x]) : (short)0;
    b1f[i] = b1[g*4 + i];
    b2f[i] = (g == 0) ? b2[i] : 0.f;
  }
  const __hip_bfloat16* qbase = qp + ((size_t)(b*NN + i0 + x))*128 + g*4;
  bf16x4 qf1[NH], qf2[NH];
  #pragma unroll
  for (int h = 0; h < NH; ++h){
    qf1[h] = *reinterpret_cast<const bf16x4*>(qbase + h*32);
    qf2[h] = *reinterpret_cast<const bf16x4*>(qbase + h*32 + 16);
  }

  f32x4 ctx[NH][2];
  float l_[NH];
  #pragma unroll
  for (int h = 0; h < NH; ++h){
    l_[h] = 0.f;
    #pragma unroll
    for (int mf = 0; mf < 2; ++mf)
      #pragma unroll
      for (int r = 0; r < 4; ++r) ctx[h][mf][r] = 0.f;
  }

  const float* pair_i = pair + (((size_t)b*NN + i0)*NN)*PD;
  const float* mask_i = mask + ((size_t)b*NN + i0 + x)*NN;
  const bf16x4* kq2f = reinterpret_cast<const bf16x4*>(kq2);
  const bf16x4* vq2f = reinterpret_cast<const bf16x4*>(vq2);

  // batch q covers i-rows {2q, 2q+1}, each a 4KB-contiguous 64-j span
  auto LOADB = [&](f32x4 (&buf)[8], int j0, int q){
    const float* pjb = pair_i + (size_t)(2*q)*NN*PD + ((size_t)(j0 + x))*PD + g*4;
    #pragma unroll
    for (int u = 0; u < 8; ++u)
      buf[u] = __builtin_nontemporal_load(
                 reinterpret_cast<const f32x4*>(pjb + (size_t)(u>>2)*NN*PD + (u&3)*16*PD));
  };
  // MLP compute -> bf16 rel into rr0 (layout/decode verified R12/R13/R15)
  auto COMPB = [&](const f32x4 (&buf)[8], int q, unsigned short* rr0){
    #pragma unroll
    for (int u = 0; u < 8; ++u){
      const int il = 2*q + (u>>2);
      bf16x4 pb;
      #pragma unroll
      for (int i = 0; i < 4; ++i) pb[i] = bfs(buf[u][i]);
      f32x4 hid = mfma16(w1t, pb, b1f);            // hiddenT: row=pout, col=j
      bf16x4 hs;
      #pragma unroll
      for (int r = 0; r < 4; ++r){
        const float hv = hid[r];
        hs[r] = bfs(hv * fastrcp(1.f + __expf(-hv)));
      }
      f32x4 rel = mfma16(w2t, hs, b2f);            // relT: row=h (g==0), col=j
      if (g == 0){
        bf16x4 rb;
        #pragma unroll
        for (int r = 0; r < 4; ++r) rb[r] = bfs(rel[r]);
        *reinterpret_cast<bf16x4*>(rr0 + il*264 + ((u&3)*16 + x)*4) = rb;
      }
    }
  };
  // one attention unit a = t*4+h on tile at j0c, rel from rlc
  auto ATTN = [&](int j0c, int a, const unsigned short* rlc,
                  f32x4& mb, u32x4& rq0, u32x4& rq1){
    const int t = a >> 2, h = a & 3;
    if (h == 0){
      const f32x4 mq = *reinterpret_cast<const f32x4*>(mask_i + j0c + t*16 + g*4);
      #pragma unroll
      for (int r = 0; r < 4; ++r) mb[r] = (mq[r] >= 0.5f) ? 0.f : NEGBIG;
      const unsigned short* rlr = rlc + x*264 + (t*16 + g*4)*4;   // row il=x
      rq0 = *reinterpret_cast<const u32x4*>(rlr);
      rq1 = *reinterpret_cast<const u32x4*>(rlr + 8);
    }
    f32x4 cin;
    cin[0] = bfbits(rq0[(h>>1)    ], h & 1) + mb[0];
    cin[1] = bfbits(rq0[2 + (h>>1)], h & 1) + mb[1];
    cin[2] = bfbits(rq1[(h>>1)    ], h & 1) + mb[2];
    cin[3] = bfbits(rq1[2 + (h>>1)], h & 1) + mb[3];
    const int blk = (b*NH + h)*128 + (j0c >> 4) + t;
    const bf16x4 k00 = kq2f[(size_t)blk*128 + lane];        // 512B coalesced
    const bf16x4 k01 = kq2f[(size_t)blk*128 + 64 + lane];
    f32x4 sv = mfma16(k01, qf2[h], mfma16(k00, qf1[h], cin));  // S^T[j][i=x]
    f32x4 p;
    #pragma unroll
    for (int r = 0; r < 4; ++r) p[r] = __expf(fminf(sv[r], SCLAMP));
    l_[h] += (p[0] + p[1]) + (p[2] + p[3]);
    bf16x4 pbv;                          // P^T already in PV B-frag layout
    #pragma unroll
    for (int r = 0; r < 4; ++r) pbv[r] = bfs(p[r]);
    #pragma unroll
    for (int mf = 0; mf < 2; ++mf){
      const bf16x4 va = vq2f[((size_t)blk*2 + mf)*64 + lane]; // 512B coalesced
      ctx[h][mf] = mfma16(va, pbv, ctx[h][mf]);
    }
  };

  f32x4 b0[8], b1r[8], b2r[8], b3[8];
  const int nsteps = jchunk >> 6;          // 64-wide j-tiles (S=8 -> 4)

  // ---- prologue: MLP of tile 0 into rl2[0], distance-2 pipelined ----
  LOADB(b0, j0b, 0);
  LOADB(b1r, j0b, 1);
  {
    unsigned short* rn = rl2;
    LOADB(b2r, j0b, 2);                      COMPB(b0, 0, rn);
    LOADB(b3, j0b, 3);                       COMPB(b1r, 1, rn);
    LOADB(b0, j0b, 4);                       COMPB(b2r, 2, rn);
    LOADB(b1r, j0b, 5);                      COMPB(b3, 3, rn);
    LOADB(b2r, j0b, 6);                      COMPB(b0, 4, rn);
    LOADB(b3, j0b, 7);                       COMPB(b1r, 5, rn);
    if (nsteps > 1) LOADB(b0, j0b + 64, 0);  COMPB(b2r, 6, rn);
    if (nsteps > 1) LOADB(b1r, j0b + 64, 1); COMPB(b3, 7, rn);
  }

  // ---- main: attention(tile jt) zipped with MLP(tile jt+1), distance-2 loads ----
  for (int jt = 0; jt < nsteps; ++jt){
    const int j0 = j0b + (jt << 6);
    const bool hasNext = (jt + 1 < nsteps);
    const bool hasNext2 = (jt + 2 < nsteps);
    const unsigned short* rlc = rl2 + (jt & 1)*(16*264);
    unsigned short* rln = rl2 + (((jt & 1)^1))*(16*264);
    f32x4 mb; u32x4 rq0, rq1;
    if (hasNext){ LOADB(b2r, j0 + 64, 2);                  COMPB(b0, 0, rln); }
    ATTN(j0, 0, rlc, mb, rq0, rq1);  ATTN(j0, 1, rlc, mb, rq0, rq1);
    if (hasNext){ LOADB(b3, j0 + 64, 3);                   COMPB(b1r, 1, rln); }
    ATTN(j0, 2, rlc, mb, rq0, rq1);  ATTN(j0, 3, rlc, mb, rq0, rq1);
    if (hasNext){ LOADB(b0, j0 + 64, 4);                   COMPB(b2r, 2, rln); }
    ATTN(j0, 4, rlc, mb, rq0, rq1);  ATTN(j0, 5, rlc, mb, rq0, rq1);
    if (hasNext){ LOADB(b1r, j0 + 64, 5);                  COMPB(b3, 3, rln); }
    ATTN(j0, 6, rlc, mb, rq0, rq1);  ATTN(j0, 7, rlc, mb, rq0, rq1);
    if (hasNext){ LOADB(b2r, j0 + 64, 6);                  COMPB(b0, 4, rln); }
    ATTN(j0, 8, rlc, mb, rq0, rq1);  ATTN(j0, 9, rlc, mb, rq0, rq1);
    if (hasNext){ LOADB(b3, j0 + 64, 7);                   COMPB(b1r, 5, rln); }
    ATTN(j0, 10, rlc, mb, rq0, rq1); ATTN(j0, 11, rlc, mb, rq0, rq1);
    if (hasNext){ if (hasNext2) LOADB(b0, j0 + 128, 0);    COMPB(b2r, 6, rln); }
    ATTN(j0, 12, rlc, mb, rq0, rq1); ATTN(j0, 13, rlc, mb, rq0, rq1);
    if (hasNext){ if (hasNext2) LOADB(b1r, j0 + 128, 1);   COMPB(b3, 7, rln); }
    ATTN(j0, 14, rlc, mb, rq0, rq1); ATTN(j0, 15, rlc, mb, rq0, rq1);
  }

  // reduce l across the 4 g-groups (j subsets) once per wave
  #pragma unroll
  for (int h = 0; h < NH; ++h){
    float l = l_[h];
    l += __shfl_xor(l, 16);
    l += __shfl_xor(l, 32);
    l_[h] = l;
  }

  float* pc = Pctx + ((size_t)((b*128 + it)*S + s))*2048;   // [128 d-pad][16 i]
  #pragma unroll
  for (int h = 0; h < NH; ++h)
    #pragma unroll
    for (int mf = 0; mf < 2; ++mf)
      #pragma unroll
      for (int r = 0; r < 4; ++r)
        pc[(h*32 + mf*16 + g*4 + r)*16 + x] = ctx[h][mf][r];
  if (g == 0){
    float* pm = Pml + ((size_t)((b*128 + it)*S + s))*64;    // l only
    #pragma unroll
    for (int h = 0; h < NH; ++h)
      pm[h*16 + x] = l_[h];
  }
}

// ---------------- Kernel C: merge splits (plain sums), out-proj, residual ----------------
__global__ __launch_bounds__(256) void kC(
    const float* __restrict__ Pctx, const float* __restrict__ Pml,
    const float* __restrict__ nodes, const float* __restrict__ Wo,
    float* __restrict__ out, const int S)
{
  __shared__ float invl[64];
  __shared__ float ctxl[16][100];
  const int b  = blockIdx.x >> 7;
  const int it = blockIdx.x & 127;
  const int tid = threadIdx.x;
  const float* pm = Pml + ((size_t)((b*128 + it))*S)*64;
  if (tid < 64){
    float lt = 0.f;
    for (int s2 = 0; s2 < S; ++s2) lt += pm[s2*64 + tid];
    invl[tid] = 1.f / lt;
  }
  __syncthreads();
  const float* pc = Pctx + ((size_t)((b*128 + it))*S)*2048;
  for (int idx = tid; idx < DIM*16; idx += 256){
    const int d = idx >> 4, i = idx & 15;
    const int h = d / DH, dh = d - h*DH;
    const int d128 = h*32 + dh;
    float acc = 0.f;
    for (int s2 = 0; s2 < S; ++s2)
      acc += pc[(size_t)s2*2048 + d128*16 + i];
    ctxl[i][d] = acc * invl[(h<<4) + i];
  }
  __syncthreads();
  const float* nr = nodes + ((size_t)(b*NN + (it<<4)))*DIM;
  float* outr = out + ((size_t)(b*NN + (it<<4)))*DIM;
  for (int idx = tid; idx < 16*DIM; idx += 256){
    const int i = idx / DIM, dout = idx - i*DIM;
    float acc = nr[idx];
    #pragma unroll 8
    for (int dd = 0; dd < DIM; ++dd)
      acc += ctxl[i][dd] * Wo[dd*DIM + dout];
    outr[idx] = acc;
  }
}

extern "C" void kernel_launch(void* const* d_in, const int* in_sizes, int n_in,
                              void* d_out, int out_size, void* d_ws, size_t ws_size,
                              hipStream_t stream)
{
  (void)in_sizes; (void)n_in; (void)out_size;
  const float* nodes = (const float*)d_in[0];
  const float* pair  = (const float*)d_in[1];
  const float* maskp = (const float*)d_in[2];
  const float* gamma = (const float*)d_in[3];
  const float* beta  = (const float*)d_in[4];
  const float* Wq    = (const float*)d_in[5];
  const float* Wk    = (const float*)d_in[6];
  const float* Wv    = (const float*)d_in[7];
  const float* W1    = (const float*)d_in[8];
  const float* b1    = (const float*)d_in[9];
  const float* W2    = (const float*)d_in[10];
  const float* b2    = (const float*)d_in[11];
  const float* Wo    = (const float*)d_in[12];
  float* out = (float*)d_out;

  const size_t MB = (size_t)1 << 20;
  __hip_bfloat16* qp   = (__hip_bfloat16*)d_ws;                 // 1MB [B][N][H][32]
  unsigned short* kq2  = (unsigned short*)((char*)d_ws + MB);   // 1MB frag-swizzled K
  unsigned short* vq2  = (unsigned short*)((char*)d_ws + 2*MB); // 1MB frag-swizzled V
  int S = 8;                                                    // j-splits
  while (S > 1 && 3*MB + (size_t)S*(2*MB + 64*1024) > ws_size) S >>= 1;
  float* Pctx = (float*)((char*)d_ws + 3*MB);                   // [B*128][S][128][16]
  float* Pml  = (float*)((char*)d_ws + 3*MB + (size_t)S*2*MB);

  hipLaunchKernelGGL(kA, dim3(512), dim3(256), 0, stream,
                     nodes, gamma, beta, Wq, Wk, Wv, qp, kq2, vq2);
  hipLaunchKernelGGL(kB, dim3(NB*128*S), dim3(64), 0, stream,
                     pair, maskp, qp, kq2, vq2, W1, b1, W2, b2, Pctx, Pml, S);
  hipLaunchKernelGGL(kC, dim3(256), dim3(256), 0, stream,
                     Pctx, Pml, nodes, Wo, out, S);
}

// Round 18
// 150.437 us; speedup vs baseline: 1.5737x; 1.5737x over previous
//
#include <hip/hip_runtime.h>
#include <hip/hip_bf16.h>

// Problem constants
#define NB 2
#define NN 2048
#define DIM 96
#define NH 4
#define DH 24
#define PD 16
#define SCALE 0.2041241452319315f   // 1/sqrt(24)
#define NEGBIG -1e30f
#define SCLAMP 30.0f                // exp-arg clamp; exact for realistic logits

typedef __attribute__((ext_vector_type(4))) short bf16x4;
typedef __attribute__((ext_vector_type(4))) float f32x4;
typedef __attribute__((ext_vector_type(4))) unsigned int u32x4;

static __device__ __forceinline__ short bfs(float x){
  __hip_bfloat16 h = __float2bfloat16(x);
  return __builtin_bit_cast(short, h);
}

static __device__ __forceinline__ float fastrcp(float x){
#if __has_builtin(__builtin_amdgcn_rcpf)
  return __builtin_amdgcn_rcpf(x);
#else
  return 1.f / x;
#endif
}

// bf16 halfword -> f32 (hi selects upper half of the u32)
static __device__ __forceinline__ float bfbits(unsigned int u, int hi){
  return __builtin_bit_cast(float, hi ? (u & 0xFFFF0000u) : (u << 16));
}

// D = A(16x16) * B(16x16) + C, bf16 in, f32 accum. Layout (lane l, x=l&15, g=l>>4):
//   A: A[row=x][k=g*4+i] ; B: B[k=g*4+i][col=x] ; C/D: D[row=g*4+r][col=x]
static __device__ __forceinline__ f32x4 mfma16(bf16x4 a, bf16x4 b, f32x4 c){
#if __has_builtin(__builtin_amdgcn_mfma_f32_16x16x16bf16_1k)
  return __builtin_amdgcn_mfma_f32_16x16x16bf16_1k(a, b, c, 0, 0, 0);
#else
  asm volatile("v_mfma_f32_16x16x16_bf16 %0, %1, %2, %0" : "+v"(c) : "v"(a), "v"(b));
  return c;
#endif
}

// ---------------- Kernel A: LayerNorm + QKV projection (8 rows/block) ----------------
// K/V written pre-swizzled into MFMA fragment order (R14 layout, verified):
//  K: kq2[(b*NH+h)*128 + jt] 1KB block: bytes l*8 = K[jt*16+(l&15)][k=(l>>4)*4..+3]
//     (k00), bytes 512+l*8 with k+=16 (k01; k>=24 zero).
//  V: vq2[((b*NH+h)*128 + jt)*2 + mf] 512B: bytes l*8 = V[jt*16+(l>>4)*4+i][mf*16+(l&15)].
__global__ __launch_bounds__(256) void kA(
    const float* __restrict__ nodes,
    const float* __restrict__ gamma, const float* __restrict__ beta,
    const float* __restrict__ Wq, const float* __restrict__ Wk, const float* __restrict__ Wv,
    __hip_bfloat16* __restrict__ qp, unsigned short* __restrict__ kq2,
    unsigned short* __restrict__ vq2)
{
  __shared__ __align__(16) float hl[8][100];
  const int b  = blockIdx.x >> 8;
  const int n0 = (blockIdx.x & 255) << 3;
  const int tid = threadIdx.x;
  const float* np = nodes + ((size_t)(b*NN + n0))*DIM;
  for (int idx = tid; idx < 8*DIM; idx += 256){
    const int r = idx/DIM; hl[r][idx - r*DIM] = np[idx];
  }
  __syncthreads();
  const int r8 = tid >> 5, c32 = tid & 31;
  float s = 0.f, s2 = 0.f;
  for (int k2 = c32; k2 < DIM; k2 += 32){ float v = hl[r8][k2]; s += v; s2 += v*v; }
  #pragma unroll
  for (int off = 1; off < 32; off <<= 1){ s += __shfl_xor(s, off); s2 += __shfl_xor(s2, off); }
  const float mu = s*(1.f/DIM);
  const float rs = rsqrtf(s2*(1.f/DIM) - mu*mu + 1e-5f);
  for (int k2 = c32; k2 < DIM; k2 += 32)
    hl[r8][k2] = (hl[r8][k2] - mu)*rs*gamma[k2] + beta[k2];
  __syncthreads();
  for (int c = tid; c < 3*DIM; c += 256){
    const int mat = c/DIM, d = c - mat*DIM;
    const float* W = (mat == 0) ? Wq : ((mat == 1) ? Wk : Wv);
    float acc[8];
    #pragma unroll
    for (int r = 0; r < 8; ++r) acc[r] = 0.f;
    #pragma unroll 4
    for (int kk = 0; kk < DIM; ++kk){
      const float w = W[kk*DIM + d];
      #pragma unroll
      for (int r = 0; r < 8; ++r) acc[r] += hl[r][kk] * w;
    }
    const int hh = d / DH, dh = d - hh*DH;
    if (mat == 0){
      #pragma unroll
      for (int r = 0; r < 8; ++r)
        qp[((size_t)(b*NN + n0 + r))*128 + hh*32 + dh] = __float2bfloat16(acc[r] * SCALE);
    } else if (mat == 1){
      const int halfsel = dh >> 4;
      const int gk = (dh - halfsel*16) >> 2;
      #pragma unroll
      for (int r = 0; r < 8; ++r){
        const int n = n0 + r;
        const size_t base = ((size_t)(b*NH + hh)*128 + (n>>4))*512;
        kq2[base + halfsel*256 + (gk*16 + (n&15))*4 + (dh&3)] =
            (unsigned short)bfs(acc[r]);
      }
    } else {
      const int mf = dh >> 4, xx = dh & 15;
      #pragma unroll
      for (int r = 0; r < 8; ++r){
        const int n = n0 + r;
        const size_t blk = ((size_t)(b*NH + hh)*128 + (n>>4))*2 + mf;
        vq2[blk*256 + (((n&15)>>2)*16 + xx)*4 + (n&3)] = (unsigned short)bfs(acc[r]);
      }
    }
  }
  {
    const int r = tid >> 5, hh = (tid >> 3) & 3, t = tid & 7;
    const int n = n0 + r;
    const int dh = 24 + t;
    qp[((size_t)(b*NN + n))*128 + hh*32 + dh] = __float2bfloat16(0.f);
    const size_t kbase = ((size_t)(b*NH + hh)*128 + (n>>4))*512;
    kq2[kbase + 256 + (((8 + t)>>2)*16 + (n&15))*4 + (dh&3)] = 0;
    const size_t vblk = ((size_t)(b*NH + hh)*128 + (n>>4))*2 + 1;
    vq2[vblk*256 + (((n&15)>>2)*16 + 8 + t)*4 + (n&3)] = 0;
  }
}

// ---------------- Kernel B: zipped pair-MLP + masked attention ----------------
// R15 structure verbatim (64-j tiles, depth-8/distance-1 reg dbuf, bf16 rel LDS
// dbuf, zip MLP(n+1) with ATTN(n), (64,2)) EXCEPT: QK^T computed as two
// INDEPENDENT MFMAs (partial sums added) -> one MFMA latency off every ATTN
// unit's critical path, zero extra persistent registers.
__global__ __launch_bounds__(64, 2) void kB(
    const float* __restrict__ pair, const float* __restrict__ mask,
    const __hip_bfloat16* __restrict__ qp, const unsigned short* __restrict__ kq2,
    const unsigned short* __restrict__ vq2,
    const float* __restrict__ W1, const float* __restrict__ b1,
    const float* __restrict__ W2, const float* __restrict__ b2,
    float* __restrict__ Pctx, float* __restrict__ Pml, const int S)
{
  // rel bf16, double buffered: [buf][il(16)][j(64)*4h + pad(8)] stride 264 ushorts
  __shared__ __align__(16) unsigned short rl2[2*16*264];   // 16.9 KB
  const int lane = threadIdx.x & 63;
  const int gw   = blockIdx.x;
  const int s    = gw % S;
  const int it   = (gw / S) & 127;
  const int b    = gw / (S*128);
  const int i0   = it << 4;
  const int jchunk = NN / S;
  const int j0b  = s * jchunk;
  const int x = lane & 15, g = lane >> 4;

  bf16x4 w1t, w2t;
  f32x4 b1f, b2f;
  #pragma unroll
  for (int i = 0; i < 4; ++i){
    w1t[i] = bfs(W1[(g*4 + i)*16 + x]);
    w2t[i] = (x < 4) ? bfs(W2[(g*4 + i)*4 + x]) : (short)0;
    b1f[i] = b1[g*4 + i];
    b2f[i] = (g == 0) ? b2[i] : 0.f;
  }
  const __hip_bfloat16* qbase = qp + ((size_t)(b*NN + i0 + x))*128 + g*4;
  bf16x4 qf1[NH], qf2[NH];
  #pragma unroll
  for (int h = 0; h < NH; ++h){
    qf1[h] = *reinterpret_cast<const bf16x4*>(qbase + h*32);
    qf2[h] = *reinterpret_cast<const bf16x4*>(qbase + h*32 + 16);
  }

  f32x4 ctx[NH][2];
  float l_[NH];
  #pragma unroll
  for (int h = 0; h < NH; ++h){
    l_[h] = 0.f;
    #pragma unroll
    for (int mf = 0; mf < 2; ++mf)
      #pragma unroll
      for (int r = 0; r < 4; ++r) ctx[h][mf][r] = 0.f;
  }

  const float* pair_i = pair + (((size_t)b*NN + i0)*NN)*PD;
  const float* mask_i = mask + ((size_t)b*NN + i0 + x)*NN;
  const bf16x4* kq2f = reinterpret_cast<const bf16x4*>(kq2);
  const bf16x4* vq2f = reinterpret_cast<const bf16x4*>(vq2);

  // batch q covers i-rows {2q, 2q+1}, each a 4KB-contiguous 64-j span
  auto LOADB = [&](f32x4 (&buf)[8], int j0, int q){
    const float* pjb = pair_i + (size_t)(2*q)*NN*PD + ((size_t)(j0 + x))*PD + g*4;
    #pragma unroll
    for (int u = 0; u < 8; ++u)
      buf[u] = __builtin_nontemporal_load(
                 reinterpret_cast<const f32x4*>(pjb + (size_t)(u>>2)*NN*PD + (u&3)*16*PD));
  };
  // MLP compute -> bf16 rel into rr0 (layout/decode verified R12/R13/R15)
  auto COMPB = [&](const f32x4 (&buf)[8], int q, unsigned short* rr0){
    #pragma unroll
    for (int u = 0; u < 8; ++u){
      const int il = 2*q + (u>>2);
      bf16x4 pb;
      #pragma unroll
      for (int i = 0; i < 4; ++i) pb[i] = bfs(buf[u][i]);
      f32x4 hid = mfma16(w1t, pb, b1f);            // hiddenT: row=pout, col=j
      bf16x4 hs;
      #pragma unroll
      for (int r = 0; r < 4; ++r){
        const float hv = hid[r];
        hs[r] = bfs(hv * fastrcp(1.f + __expf(-hv)));
      }
      f32x4 rel = mfma16(w2t, hs, b2f);            // relT: row=h (g==0), col=j
      if (g == 0){
        bf16x4 rb;
        #pragma unroll
        for (int r = 0; r < 4; ++r) rb[r] = bfs(rel[r]);
        *reinterpret_cast<bf16x4*>(rr0 + il*264 + ((u&3)*16 + x)*4) = rb;
      }
    }
  };
  // one attention unit a = t*4+h on tile at j0c, rel from rlc.
  // QK^T as two independent MFMAs (partials summed) to cut chain latency.
  auto ATTN = [&](int j0c, int a, const unsigned short* rlc,
                  f32x4& mb, u32x4& rq0, u32x4& rq1){
    const int t = a >> 2, h = a & 3;
    if (h == 0){
      const f32x4 mq = *reinterpret_cast<const f32x4*>(mask_i + j0c + t*16 + g*4);
      #pragma unroll
      for (int r = 0; r < 4; ++r) mb[r] = (mq[r] >= 0.5f) ? 0.f : NEGBIG;
      const unsigned short* rlr = rlc + x*264 + (t*16 + g*4)*4;   // row il=x
      rq0 = *reinterpret_cast<const u32x4*>(rlr);
      rq1 = *reinterpret_cast<const u32x4*>(rlr + 8);
    }
    f32x4 cin;
    cin[0] = bfbits(rq0[(h>>1)    ], h & 1) + mb[0];
    cin[1] = bfbits(rq0[2 + (h>>1)], h & 1) + mb[1];
    cin[2] = bfbits(rq1[(h>>1)    ], h & 1) + mb[2];
    cin[3] = bfbits(rq1[2 + (h>>1)], h & 1) + mb[3];
    const int blk = (b*NH + h)*128 + (j0c >> 4) + t;
    const bf16x4 k00 = kq2f[(size_t)blk*128 + lane];        // 512B coalesced
    const bf16x4 k01 = kq2f[(size_t)blk*128 + 64 + lane];
    const f32x4 zero = {0.f, 0.f, 0.f, 0.f};
    const f32x4 sva = mfma16(k00, qf1[h], cin);             // independent
    const f32x4 svb = mfma16(k01, qf2[h], zero);            // independent
    const f32x4 sv = sva + svb;                             // S^T[j][i=x]
    f32x4 p;
    #pragma unroll
    for (int r = 0; r < 4; ++r) p[r] = __expf(fminf(sv[r], SCLAMP));
    l_[h] += (p[0] + p[1]) + (p[2] + p[3]);
    bf16x4 pbv;                          // P^T already in PV B-frag layout
    #pragma unroll
    for (int r = 0; r < 4; ++r) pbv[r] = bfs(p[r]);
    #pragma unroll
    for (int mf = 0; mf < 2; ++mf){
      const bf16x4 va = vq2f[((size_t)blk*2 + mf)*64 + lane]; // 512B coalesced
      ctx[h][mf] = mfma16(va, pbv, ctx[h][mf]);
    }
  };

  f32x4 bufA[8], bufB[8];
  const int nsteps = jchunk >> 6;          // 64-wide j-tiles (S=8 -> 4)

  // ---- prologue: full MLP for tile 0 into rl2[0] ----
  LOADB(bufA, j0b, 0);
  {
    unsigned short* rn = rl2;
    LOADB(bufB, j0b, 1);  COMPB(bufA, 0, rn);
    LOADB(bufA, j0b, 2);  COMPB(bufB, 1, rn);
    LOADB(bufB, j0b, 3);  COMPB(bufA, 2, rn);
    LOADB(bufA, j0b, 4);  COMPB(bufB, 3, rn);
    LOADB(bufB, j0b, 5);  COMPB(bufA, 4, rn);
    LOADB(bufA, j0b, 6);  COMPB(bufB, 5, rn);
    LOADB(bufB, j0b, 7);  COMPB(bufA, 6, rn);
    if (nsteps > 1) LOADB(bufA, j0b + 64, 0);
    COMPB(bufB, 7, rn);
  }

  // ---- main: attention(tile jt) zipped with MLP(tile jt+1) ----
  for (int jt = 0; jt < nsteps; ++jt){
    const int j0 = j0b + (jt << 6);
    const bool hasNext = (jt + 1 < nsteps);
    const unsigned short* rlc = rl2 + (jt & 1)*(16*264);
    unsigned short* rln = rl2 + (((jt & 1)^1))*(16*264);
    f32x4 mb; u32x4 rq0, rq1;
    #pragma unroll
    for (int q = 0; q < 8; ++q){
      if (hasNext){
        if (q & 1){
          if (q < 7)                 LOADB(bufA, j0 + 64, q + 1);
          else if (jt + 2 < nsteps)  LOADB(bufA, j0 + 128, 0);
          COMPB(bufB, q, rln);
        } else {
          LOADB(bufB, j0 + 64, q + 1);
          COMPB(bufA, q, rln);
        }
      }
      ATTN(j0, 2*q,     rlc, mb, rq0, rq1);
      ATTN(j0, 2*q + 1, rlc, mb, rq0, rq1);
    }
  }

  // reduce l across the 4 g-groups (j subsets) once per wave
  #pragma unroll
  for (int h = 0; h < NH; ++h){
    float l = l_[h];
    l += __shfl_xor(l, 16);
    l += __shfl_xor(l, 32);
    l_[h] = l;
  }

  float* pc = Pctx + ((size_t)((b*128 + it)*S + s))*2048;   // [128 d-pad][16 i]
  #pragma unroll
  for (int h = 0; h < NH; ++h)
    #pragma unroll
    for (int mf = 0; mf < 2; ++mf)
      #pragma unroll
      for (int r = 0; r < 4; ++r)
        pc[(h*32 + mf*16 + g*4 + r)*16 + x] = ctx[h][mf][r];
  if (g == 0){
    float* pm = Pml + ((size_t)((b*128 + it)*S + s))*64;    // l only
    #pragma unroll
    for (int h = 0; h < NH; ++h)
      pm[h*16 + x] = l_[h];
  }
}

// ---------------- Kernel C: merge splits (plain sums), out-proj, residual ----------------
__global__ __launch_bounds__(256) void kC(
    const float* __restrict__ Pctx, const float* __restrict__ Pml,
    const float* __restrict__ nodes, const float* __restrict__ Wo,
    float* __restrict__ out, const int S)
{
  __shared__ float invl[64];
  __shared__ float ctxl[16][100];
  const int b  = blockIdx.x >> 7;
  const int it = blockIdx.x & 127;
  const int tid = threadIdx.x;
  const float* pm = Pml + ((size_t)((b*128 + it))*S)*64;
  if (tid < 64){
    float lt = 0.f;
    for (int s2 = 0; s2 < S; ++s2) lt += pm[s2*64 + tid];
    invl[tid] = 1.f / lt;
  }
  __syncthreads();
  const float* pc = Pctx + ((size_t)((b*128 + it))*S)*2048;
  for (int idx = tid; idx < DIM*16; idx += 256){
    const int d = idx >> 4, i = idx & 15;
    const int h = d / DH, dh = d - h*DH;
    const int d128 = h*32 + dh;
    float acc = 0.f;
    for (int s2 = 0; s2 < S; ++s2)
      acc += pc[(size_t)s2*2048 + d128*16 + i];
    ctxl[i][d] = acc * invl[(h<<4) + i];
  }
  __syncthreads();
  const float* nr = nodes + ((size_t)(b*NN + (it<<4)))*DIM;
  float* outr = out + ((size_t)(b*NN + (it<<4)))*DIM;
  for (int idx = tid; idx < 16*DIM; idx += 256){
    const int i = idx / DIM, dout = idx - i*DIM;
    float acc = nr[idx];
    #pragma unroll 8
    for (int dd = 0; dd < DIM; ++dd)
      acc += ctxl[i][dd] * Wo[dd*DIM + dout];
    outr[idx] = acc;
  }
}

extern "C" void kernel_launch(void* const* d_in, const int* in_sizes, int n_in,
                              void* d_out, int out_size, void* d_ws, size_t ws_size,
                              hipStream_t stream)
{
  (void)in_sizes; (void)n_in; (void)out_size;
  const float* nodes = (const float*)d_in[0];
  const float* pair  = (const float*)d_in[1];
  const float* maskp = (const float*)d_in[2];
  const float* gamma = (const float*)d_in[3];
  const float* beta  = (const float*)d_in[4];
  const float* Wq    = (const float*)d_in[5];
  const float* Wk    = (const float*)d_in[6];
  const float* Wv    = (const float*)d_in[7];
  const float* W1    = (const float*)d_in[8];
  const float* b1    = (const float*)d_in[9];
  const float* W2    = (const float*)d_in[10];
  const float* b2    = (const float*)d_in[11];
  const float* Wo    = (const float*)d_in[12];
  float* out = (float*)d_out;

  const size_t MB = (size_t)1 << 20;
  __hip_bfloat16* qp   = (__hip_bfloat16*)d_ws;                 // 1MB [B][N][H][32]
  unsigned short* kq2  = (unsigned short*)((char*)d_ws + MB);   // 1MB frag-swizzled K
  unsigned short* vq2  = (unsigned short*)((char*)d_ws + 2*MB); // 1MB frag-swizzled V
  int S = 8;                                                    // j-splits
  while (S > 1 && 3*MB + (size_t)S*(2*MB + 64*1024) > ws_size) S >>= 1;
  float* Pctx = (float*)((char*)d_ws + 3*MB);                   // [B*128][S][128][16]
  float* Pml  = (float*)((char*)d_ws + 3*MB + (size_t)S*2*MB);

  hipLaunchKernelGGL(kA, dim3(512), dim3(256), 0, stream,
                     nodes, gamma, beta, Wq, Wk, Wv, qp, kq2, vq2);
  hipLaunchKernelGGL(kB, dim3(NB*128*S), dim3(64), 0, stream,
                     pair, maskp, qp, kq2, vq2, W1, b1, W2, b2, Pctx, Pml, S);
  hipLaunchKernelGGL(kC, dim3(256), dim3(256), 0, stream,
                     Pctx, Pml, nodes, Wo, out, S);
}